// Round 3
// baseline (37235.229 us; speedup 1.0000x reference)
//
#include <hip/hip_runtime.h>
#include <cmath>
#include <cfloat>

constexpr int H    = 1024;
constexpr int H2   = 2048;
constexpr int H3   = 3072;
constexpr int ML   = 128;
constexpr int MLp1 = 129;
constexpr int VOUT = 32000;

constexpr int NBLK = 512;
constexpr int NTHR = 256;
constexpr int NWAVES = NBLK * NTHR / 64;      // 2048
constexpr int OUT_WAVES = 2000;               // waves doing out_W matvec
constexpr int OUT_ROWS  = 16;                 // rows per wave: 2000*16 = 32000
constexpr int GH_W0 = 641;                    // first wave doing gh
constexpr int GH_NW = NWAVES - GH_W0;         // 1407 waves for 3072 gh rows
constexpr int NGRP = 16;
constexpr int GSZ  = NBLK / NGRP;             // 32 blocks per barrier group
constexpr int SPIN_LIMIT = 1 << 23;           // ~1s safety valve

// ---------------- hand-rolled grid barrier (no cooperative launch) ----------
// bar layout (ints): [0]=gen  [8]=dead  [32]=root_cnt  [64+32*g]=grp_cnt[g]
__device__ __forceinline__ bool spin_gen(int* gen, int g, int* dead) {
    int cnt = 0;
    while (__hip_atomic_load(gen, __ATOMIC_RELAXED, __HIP_MEMORY_SCOPE_AGENT) == g) {
        __builtin_amdgcn_s_sleep(1);
        if ((++cnt & 0xFFFFF) == 0) {
            if (__hip_atomic_load(dead, __ATOMIC_RELAXED, __HIP_MEMORY_SCOPE_AGENT)) return false;
            if (cnt >= SPIN_LIMIT) {
                __hip_atomic_store(dead, 1, __ATOMIC_RELAXED, __HIP_MEMORY_SCOPE_AGENT);
                return false;
            }
        }
    }
    return true;
}

__device__ __forceinline__ void gridbar(int* bar) {
    __syncthreads();
    if (threadIdx.x == 0) {
        int* gen  = bar;
        int* dead = bar + 8;
        int* root = bar + 32;
        int* grp  = bar + 64 + 32 * (blockIdx.x & (NGRP - 1));
        if (!__hip_atomic_load(dead, __ATOMIC_RELAXED, __HIP_MEMORY_SCOPE_AGENT)) {
            __threadfence();   // release: make this block's writes agent-visible
            const int g = __hip_atomic_load(gen, __ATOMIC_RELAXED, __HIP_MEMORY_SCOPE_AGENT);
            if (__hip_atomic_fetch_add(grp, 1, __ATOMIC_ACQ_REL, __HIP_MEMORY_SCOPE_AGENT) == GSZ - 1) {
                __hip_atomic_store(grp, 0, __ATOMIC_RELAXED, __HIP_MEMORY_SCOPE_AGENT);
                if (__hip_atomic_fetch_add(root, 1, __ATOMIC_ACQ_REL, __HIP_MEMORY_SCOPE_AGENT) == NGRP - 1) {
                    __hip_atomic_store(root, 0, __ATOMIC_RELAXED, __HIP_MEMORY_SCOPE_AGENT);
                    __hip_atomic_store(gen, g + 1, __ATOMIC_RELEASE, __HIP_MEMORY_SCOPE_AGENT);
                } else {
                    spin_gen(gen, g, dead);
                }
            } else {
                spin_gen(gen, g, dead);
            }
            __threadfence();   // acquire: see other blocks' writes
        }
    }
    __syncthreads();
}

__device__ __forceinline__ float wave_sum(float v) {
#pragma unroll
    for (int off = 32; off; off >>= 1) v += __shfl_xor(v, off, 64);
    return v;
}

__device__ __forceinline__ float sigmf(float x) { return 1.f / (1.f + expf(-x)); }

// Reduce per-wave (max, sumexp, argmax) partials into (lse, argmax-token).
// Deterministic and identical across all waves (same data, same op order).
__device__ __forceinline__ void reduce_partials(const float* __restrict__ pmax,
                                                const float* __restrict__ psum,
                                                const int* __restrict__ parg,
                                                int lane, float& lse, int& tok) {
    float m = -FLT_MAX, s = 0.f, bm = -FLT_MAX;
    int bi = 0x7fffffff;
    for (int i = lane; i < OUT_WAVES; i += 64) {
        const float mi = pmax[i], si = psum[i];
        const int ai = parg[i];
        const float nm = fmaxf(m, mi);
        s = s * expf(m - nm) + si * expf(mi - nm);
        m = nm;
        if (mi > bm || (mi == bm && ai < bi)) { bm = mi; bi = ai; }
    }
#pragma unroll
    for (int off = 32; off; off >>= 1) {
        const float mo  = __shfl_xor(m, off, 64);
        const float so  = __shfl_xor(s, off, 64);
        const float bmo = __shfl_xor(bm, off, 64);
        const int   bio = __shfl_xor(bi, off, 64);
        const float nm = fmaxf(m, mo);
        s = s * expf(m - nm) + so * expf(mo - nm);   // commutative: bitwise same on both partners
        m = nm;
        if (bmo > bm || (bmo == bm && bio < bi)) { bm = bmo; bi = bio; }
    }
    lse = m + logf(s);
    tok = bi;
}

__global__ __launch_bounds__(NTHR, 2)
void seq2seq_kernel(const int* __restrict__ tokens,
                    const float* __restrict__ enc_emb,
                    const float* __restrict__ enc_Wih,
                    const float* __restrict__ enc_Whh,
                    const float* __restrict__ enc_bih,
                    const float* __restrict__ enc_bhh,
                    const float* __restrict__ dec_emb,
                    const float* __restrict__ attn_W,
                    const float* __restrict__ attn_b,
                    const float* __restrict__ comb_W,
                    const float* __restrict__ comb_b,
                    const float* __restrict__ dec_Wih,
                    const float* __restrict__ dec_Whh,
                    const float* __restrict__ dec_bih,
                    const float* __restrict__ dec_bhh,
                    const float* __restrict__ out_W,
                    const float* __restrict__ out_b,
                    float* __restrict__ out,
                    int* __restrict__ bar,
                    float* __restrict__ fws)
{
    const int tid  = blockIdx.x * NTHR + threadIdx.x;
    const int w    = tid >> 6;
    const int lane = tid & 63;

    // float workspace layout (fws = ws + 4KB barrier area)
    float* enc_out = fws;                       // (ML+1)*H = 132096
    float* hbuf    = enc_out + MLp1 * H;        // 2*H (16B aligned)
    float* gh      = hbuf + 2 * H;              // H3
    float* scores  = gh + H3;                   // MLp1
    float* ctxv    = scores + MLp1;             // H
    float* combv   = ctxv + H;                  // H
    float* logits  = combv + H;                 // VOUT
    float* pmax    = logits + VOUT;             // OUT_WAVES
    float* psum    = pmax + OUT_WAVES;          // OUT_WAVES
    int*   parg    = (int*)(psum + OUT_WAVES);  // OUT_WAVES

    // ---- init (ws is poisoned 0xAA) ----
    if (tid < H) hbuf[tid] = 0.f;                              // h0 = 0
    else if (tid < 2 * H) enc_out[ML * H + (tid - H)] = 0.f;   // encoder_outputs[ML] = 0
    gridbar(bar);

    // ---- encoder: 1 grid barrier per step; Wih@x folded in (weights L2-resident) ----
    for (int t = 0; t < ML; ++t) {
        const float* hc = hbuf + (t & 1) * H;
        if (w < H) {
            const int j = w;
            const float* x = enc_emb + (size_t)tokens[t] * H;
            float hr[16], xr[16];
#pragma unroll
            for (int k = 0; k < 16; ++k) { hr[k] = hc[lane + 64 * k]; xr[k] = x[lane + 64 * k]; }
            const float* ur = enc_Wih + (size_t)j * H;
            const float* uz = enc_Wih + (size_t)(j + H) * H;
            const float* un = enc_Wih + (size_t)(j + 2 * H) * H;
            const float* wr = enc_Whh + (size_t)j * H;
            const float* wz = enc_Whh + (size_t)(j + H) * H;
            const float* wn = enc_Whh + (size_t)(j + 2 * H) * H;
            float ir = 0.f, iz = 0.f, in_ = 0.f, dr = 0.f, dz = 0.f, dn = 0.f;
#pragma unroll
            for (int k = 0; k < 16; ++k) {
                const int idx = lane + 64 * k;
                const float xv = xr[k], hv = hr[k];
                ir  = fmaf(ur[idx], xv, ir);
                iz  = fmaf(uz[idx], xv, iz);
                in_ = fmaf(un[idx], xv, in_);
                dr  = fmaf(wr[idx], hv, dr);
                dz  = fmaf(wz[idx], hv, dz);
                dn  = fmaf(wn[idx], hv, dn);
            }
            ir = wave_sum(ir); iz = wave_sum(iz); in_ = wave_sum(in_);
            dr = wave_sum(dr); dz = wave_sum(dz); dn = wave_sum(dn);
            if (lane == 0) {
                const float r = sigmf(ir + enc_bih[j] + dr + enc_bhh[j]);
                const float z = sigmf(iz + enc_bih[j + H] + dz + enc_bhh[j + H]);
                const float n = tanhf(fmaf(r, dn + enc_bhh[j + 2 * H], in_ + enc_bih[j + 2 * H]));
                const float h2 = (1.f - z) * n + z * hc[j];
                hbuf[((t + 1) & 1) * H + j] = h2;
                enc_out[t * H + j] = h2;
            }
        }
        gridbar(bar);
    }

    // ---- decoder: 5 grid barriers per step ----
    float lse = 0.f;
    int tok = 0;   // SOS

    for (int d = 0; d < ML; ++d) {
        // Phase A: (redundant) lse/argmax reduce; then logp write | attn scores | gh
        if (d > 0) {
            reduce_partials(pmax, psum, parg, lane, lse, tok);
            if (tid < VOUT) out[(size_t)(d - 1) * VOUT + tid] = logits[tid] - lse;
        }
        const float* hc  = hbuf + (d & 1) * H;
        const float* emb = dec_emb + (size_t)tok * H;

        if (w >= 512 && w < 512 + MLp1) {
            // attention scores: row (w-512) of attn_W @ [emb; h] + attn_b
            const int row = w - 512;
            const float* ap = attn_W + (size_t)row * H2;
            float acc = 0.f;
#pragma unroll
            for (int k = 0; k < 16; ++k) acc = fmaf(ap[lane + 64 * k], emb[lane + 64 * k], acc);
#pragma unroll
            for (int k = 0; k < 16; ++k) acc = fmaf(ap[H + lane + 64 * k], hc[lane + 64 * k], acc);
            acc = wave_sum(acc);
            if (lane == 0) scores[row] = acc + attn_b[row];
        } else if (w >= GH_W0) {
            // gh = dec_Whh @ h + b_hh (depends only on h — hoisted here)
            float hr[16];
#pragma unroll
            for (int k = 0; k < 16; ++k) hr[k] = hc[lane + 64 * k];
            for (int r = w - GH_W0; r < H3; r += GH_NW) {
                const float* wp = dec_Whh + (size_t)r * H;
                float acc = 0.f;
#pragma unroll
                for (int k = 0; k < 16; ++k) acc = fmaf(wp[lane + 64 * k], hr[k], acc);
                acc = wave_sum(acc);
                if (lane == 0) gh[r] = acc + dec_bhh[r];
            }
        }
        gridbar(bar);

        // Phase B: softmax (redundant per-thread) + ctx = attn_w @ encoder_outputs
        if (tid < H) {
            float m = scores[0];
            for (int i = 1; i < MLp1; ++i) m = fmaxf(m, scores[i]);
            float ssum = 0.f, c = 0.f;
            for (int i = 0; i < MLp1; ++i) {
                const float e = expf(scores[i] - m);
                ssum += e;
                c = fmaf(e, enc_out[i * H + tid], c);
            }
            ctxv[tid] = c / ssum;
        }
        gridbar(bar);

        // Phase C: comb = relu(comb_W @ [emb; ctx] + comb_b)
        if (w < H) {
            const int j = w;
            const float* wp = comb_W + (size_t)j * H2;
            float acc = 0.f;
#pragma unroll
            for (int k = 0; k < 16; ++k) acc = fmaf(wp[lane + 64 * k], emb[lane + 64 * k], acc);
#pragma unroll
            for (int k = 0; k < 16; ++k) acc = fmaf(wp[H + lane + 64 * k], ctxv[lane + 64 * k], acc);
            acc = wave_sum(acc);
            if (lane == 0) combv[j] = fmaxf(acc + comb_b[j], 0.f);
        }
        gridbar(bar);

        // Phase D: gi = dec_Wih @ comb, then gates -> h2
        if (w < H) {
            const int j = w;
            float cr[16];
#pragma unroll
            for (int k = 0; k < 16; ++k) cr[k] = combv[lane + 64 * k];
            const float* wr = dec_Wih + (size_t)j * H;
            const float* wz = dec_Wih + (size_t)(j + H) * H;
            const float* wn = dec_Wih + (size_t)(j + 2 * H) * H;
            float dr = 0.f, dz = 0.f, dn = 0.f;
#pragma unroll
            for (int k = 0; k < 16; ++k) {
                const int idx = lane + 64 * k;
                const float cv = cr[k];
                dr = fmaf(wr[idx], cv, dr);
                dz = fmaf(wz[idx], cv, dz);
                dn = fmaf(wn[idx], cv, dn);
            }
            dr = wave_sum(dr); dz = wave_sum(dz); dn = wave_sum(dn);
            if (lane == 0) {
                const float r = sigmf(dr + dec_bih[j] + gh[j]);
                const float z = sigmf(dz + dec_bih[j + H] + gh[j + H]);
                const float n = tanhf(fmaf(r, gh[j + 2 * H], dn + dec_bih[j + 2 * H]));
                const float h2 = (1.f - z) * n + z * hc[j];
                hbuf[((d + 1) & 1) * H + j] = h2;
            }
        }
        gridbar(bar);

        // Phase E: logits = out_W @ h2 + out_b, with online max/sumexp/argmax
        if (w < OUT_WAVES) {
            const float4* h4p = (const float4*)(hbuf + ((d + 1) & 1) * H);
            float4 h4[4];
#pragma unroll
            for (int q = 0; q < 4; ++q) h4[q] = h4p[lane + 64 * q];
            float m = -FLT_MAX, s = 0.f;
            int bi = 0;
            for (int rr = 0; rr < OUT_ROWS; ++rr) {
                const int row = w * OUT_ROWS + rr;
                const float4* wp = (const float4*)(out_W + (size_t)row * H);
                float acc = 0.f;
#pragma unroll
                for (int q = 0; q < 4; ++q) {
                    const float4 wv = wp[lane + 64 * q];
                    acc = fmaf(wv.x, h4[q].x, acc);
                    acc = fmaf(wv.y, h4[q].y, acc);
                    acc = fmaf(wv.z, h4[q].z, acc);
                    acc = fmaf(wv.w, h4[q].w, acc);
                }
                acc = wave_sum(acc) + out_b[row];
                if (lane == 0) logits[row] = acc;
                if (acc > m) { s = s * expf(m - acc) + 1.f; m = acc; bi = row; }
                else         { s += expf(acc - m); }
            }
            if (lane == 0) { pmax[w] = m; psum[w] = s; parg[w] = bi; }
        }
        gridbar(bar);
    }

    // final logp row (step ML-1)
    reduce_partials(pmax, psum, parg, lane, lse, tok);
    if (tid < VOUT) out[(size_t)(ML - 1) * VOUT + tid] = logits[tid] - lse;
}

extern "C" void kernel_launch(void* const* d_in, const int* in_sizes, int n_in,
                              void* d_out, int out_size, void* d_ws, size_t ws_size,
                              hipStream_t stream) {
    const int*   tokens  = (const int*)d_in[0];
    // d_in[1] = max_length scalar (compile-time ML=128)
    const float* enc_emb = (const float*)d_in[2];
    const float* enc_Wih = (const float*)d_in[3];
    const float* enc_Whh = (const float*)d_in[4];
    const float* enc_bih = (const float*)d_in[5];
    const float* enc_bhh = (const float*)d_in[6];
    const float* dec_emb = (const float*)d_in[7];
    const float* attn_W  = (const float*)d_in[8];
    const float* attn_b  = (const float*)d_in[9];
    const float* comb_W  = (const float*)d_in[10];
    const float* comb_b  = (const float*)d_in[11];
    const float* dec_Wih = (const float*)d_in[12];
    const float* dec_Whh = (const float*)d_in[13];
    const float* dec_bih = (const float*)d_in[14];
    const float* dec_bhh = (const float*)d_in[15];
    const float* out_W   = (const float*)d_in[16];
    const float* out_b   = (const float*)d_in[17];
    float* out = (float*)d_out;
    int*   bar = (int*)d_ws;
    float* fws = (float*)((char*)d_ws + 4096);

    // zero the barrier area (ws is re-poisoned 0xAA before every timed launch)
    hipMemsetAsync(d_ws, 0, 4096, stream);

    hipLaunchKernelGGL(seq2seq_kernel, dim3(NBLK), dim3(NTHR), 0, stream,
                       tokens, enc_emb, enc_Wih, enc_Whh, enc_bih, enc_bhh,
                       dec_emb, attn_W, attn_b, comb_W, comb_b,
                       dec_Wih, dec_Whh, dec_bih, dec_bhh, out_W, out_b,
                       out, bar, fws);
}